// Round 2
// baseline (1443.162 us; speedup 1.0000x reference)
//
#include <hip/hip_runtime.h>

#define NSITES 1000000
#define CCH 64
#define EPS_BN 1e-5f
#define INV_N (1.0f / 1000000.0f)

typedef __bf16 bf16x8 __attribute__((ext_vector_type(8)));
typedef float f32x4 __attribute__((ext_vector_type(4)));
typedef unsigned short ushort_t;

__device__ __forceinline__ unsigned short f2bf(float x) {
    __bf16 h = (__bf16)x;
    return __builtin_bit_cast(unsigned short, h);
}
__device__ __forceinline__ float bf2f(unsigned short u) {
    return (float)__builtin_bit_cast(__bf16, u);
}

// BN1+ReLU applied to a packed pair of bf16 (identical math to the old act_kernel:
// f32 unpack -> a*x+b -> relu -> bf16 round). Bit-identical to the former h1 pass.
__device__ __forceinline__ unsigned int actu32(unsigned int u, float a0, float b0,
                                               float a1, float b1) {
    float x0 = __builtin_bit_cast(float, u << 16);
    float x1 = __builtin_bit_cast(float, u & 0xffff0000u);
    float y0 = fmaxf(a0 * x0 + b0, 0.f);
    float y1 = fmaxf(a1 * x1 + b1, 0.f);
    return (unsigned int)f2bf(y0) | ((unsigned int)f2bf(y1) << 16);
}

// ---------------- prep: cast fp32->bf16 + W swizzle + stats/zero-row init ----------------
__global__ void prep_kernel(const float* __restrict__ f, ushort_t* __restrict__ o,
                            const float* __restrict__ W1, const float* __restrict__ W2,
                            ushort_t* __restrict__ W1s, ushort_t* __restrict__ W2s,
                            float* __restrict__ stats, int total16) {
    int gtid = blockIdx.x * blockDim.x + threadIdx.x;
    if (gtid < 73728) {
        // swizzle W (fp32 [9][64][64]) into B-fragment order bf16
        // u = (((tap*2+kk)*4 + nt)*64 + lane)*8 + j
        // -> W[tap][k = 32*kk + 8*(lane>>4) + j][n = 16*nt + (lane&15)]
        const float* Wg = W1;
        ushort_t* dst = W1s;
        int u = gtid;
        if (u >= 36864) { Wg = W2; dst = W2s; u -= 36864; }
        int j = u & 7;
        int lane = (u >> 3) & 63;
        int nt = (u >> 9) & 3;
        int kk = (u >> 11) & 1;
        int tap = u >> 12;
        int k = 32 * kk + 8 * (lane >> 4) + j;
        int n = 16 * nt + (lane & 15);
        dst[u] = f2bf(Wg[tap * 4096 + k * 64 + n]);
    } else if (gtid < 73984) {
        stats[gtid - 73728] = 0.f;            // sum1,sq1,sum2,sq2
    } else if (gtid < 74016) {
        ((unsigned int*)(o + (size_t)NSITES * 64))[gtid - 73984] = 0u;  // fbf zero row
    }
    int stride = gridDim.x * blockDim.x;
    for (int i = gtid; i < total16; i += stride) {
        const float4* fp = (const float4*)(f + (size_t)i * 16);
        float4 v0 = fp[0];
        float4 v1 = fp[1];
        float4 v2 = fp[2];
        float4 v3 = fp[3];
        uint4 pa, pb;
        ushort_t* up = (ushort_t*)&pa;
        up[0] = f2bf(v0.x); up[1] = f2bf(v0.y); up[2] = f2bf(v0.z); up[3] = f2bf(v0.w);
        up[4] = f2bf(v1.x); up[5] = f2bf(v1.y); up[6] = f2bf(v1.z); up[7] = f2bf(v1.w);
        ushort_t* uq = (ushort_t*)&pb;
        uq[0] = f2bf(v2.x); uq[1] = f2bf(v2.y); uq[2] = f2bf(v2.z); uq[3] = f2bf(v2.w);
        uq[4] = f2bf(v3.x); uq[5] = f2bf(v3.y); uq[6] = f2bf(v3.z); uq[7] = f2bf(v3.w);
        uint4* op = (uint4*)(o + (size_t)i * 16);
        op[0] = pa;
        op[1] = pb;
    }
}

// ---------------- A-fragment gather: 2 m-tiles x 2 k-frags, direct from global ----------------
__device__ __forceinline__ void gatherA(const ushort_t* __restrict__ fin,
                                        const int (&idxr)[2][9], int t, int quad,
                                        uint4 (&dst)[2][2], int fallback) {
#pragma unroll
    for (int mt = 0; mt < 2; ++mt) {
        int id = idxr[mt][t];
        int r = (id < 0) ? fallback : id;
        const uint4* p = (const uint4*)(fin + ((size_t)r << 6) + (quad << 3));
        dst[mt][0] = p[0];   // k = 0..31 slice
        dst[mt][1] = p[4];   // k = 32..63 slice
    }
}

// ---------------- conv kernel: barrier-free, wave = 32 sites x 64 ch ----------------
// FUSE_ACT: apply BN1+ReLU (from prev-conv stats) to gathered rows; invalid -> 0 via cndmask.
template <bool OUT_BF16, bool FUSE_ACT>
__global__ __launch_bounds__(256, 4) void conv_kernel(
    const ushort_t* __restrict__ fin,   // [N(+1)][64] bf16
    const int* __restrict__ nbr,        // [N][9]
    const ushort_t* __restrict__ Wsw,   // swizzled bf16 W fragments
    const float* __restrict__ p_sum, const float* __restrict__ p_sq,
    const float* __restrict__ p_gamma, const float* __restrict__ p_beta,
    ushort_t* __restrict__ out_bf, float* __restrict__ out_f,
    float* __restrict__ s_sum, float* __restrict__ s_sq) {

    __shared__ float bs_sum[64];
    __shared__ float bs_sq[64];
    __shared__ __align__(16) float s_a[64];
    __shared__ __align__(16) float s_b[64];

    const int tid  = threadIdx.x;
    const int wv   = tid >> 6;
    const int lane = tid & 63;
    const int quad = lane >> 4;
    const int l15  = lane & 15;
    const int sbase = blockIdx.x * 128 + wv * 32;

    if (tid < 64) {
        bs_sum[tid] = 0.f;
        bs_sq[tid] = 0.f;
        if constexpr (FUSE_ACT) {
            // per-block BN1 finalize (stats are global sums from conv1)
            float m = p_sum[tid] * INV_N;
            float v = p_sq[tid] * INV_N - m * m;
            float s = p_gamma[tid] * rsqrtf(v + EPS_BN);
            s_a[tid] = s;
            s_b[tid] = p_beta[tid] - m * s;
        }
    }
    __syncthreads();

    float af[16], bfv[16];
    if constexpr (FUSE_ACT) {
#pragma unroll
        for (int j = 0; j < 8; ++j) {
            af[j]      = s_a[quad * 8 + j];
            af[8 + j]  = s_a[32 + quad * 8 + j];
            bfv[j]     = s_b[quad * 8 + j];
            bfv[8 + j] = s_b[32 + quad * 8 + j];
        }
    }

    // preload all 18 neighbor indices (tail sites forced invalid)
    int idxr[2][9];
#pragma unroll
    for (int mt = 0; mt < 2; ++mt) {
        int s = sbase + mt * 16 + l15;
        int sc = (s < NSITES) ? s : 0;
        bool sv = (s < NSITES);
#pragma unroll
        for (int t = 0; t < 9; ++t) {
            int id = nbr[(size_t)sc * 9 + t];
            idxr[mt][t] = sv ? id : -1;
        }
    }

    f32x4 acc[2][4];
#pragma unroll
    for (int mt = 0; mt < 2; ++mt)
#pragma unroll
        for (int nt = 0; nt < 4; ++nt) acc[mt][nt] = (f32x4){0.f, 0.f, 0.f, 0.f};

    constexpr int FB = FUSE_ACT ? 0 : NSITES;  // conv1: zero row; conv2: any row, cndmask'd

    uint4 abuf[2][2][2];  // [phase][mt][kk]
    gatherA(fin, idxr, 0, quad, abuf[0], FB);

#pragma unroll
    for (int t = 0; t < 9; ++t) {
        // B fragments FIRST (so the MFMA waitcnt keeps next-tap gathers in flight)
        bf16x8 B[2][4];
#pragma unroll
        for (int kk = 0; kk < 2; ++kk)
#pragma unroll
            for (int nt = 0; nt < 4; ++nt)
                B[kk][nt] = *(const bf16x8*)(Wsw + (size_t)(((t * 2 + kk) * 4 + nt) * 64 + lane) * 8);

        if (t < 8) gatherA(fin, idxr, t + 1, quad, abuf[(t + 1) & 1], FB);

        // prepare A fragments (act + invalid->0 for conv2)
        bf16x8 afr[2][2];
#pragma unroll
        for (int mt = 0; mt < 2; ++mt) {
            uint4 r0 = abuf[t & 1][mt][0];
            uint4 r1 = abuf[t & 1][mt][1];
            if constexpr (FUSE_ACT) {
                bool inv = idxr[mt][t] < 0;
                unsigned int* p0 = (unsigned int*)&r0;
                unsigned int* p1 = (unsigned int*)&r1;
#pragma unroll
                for (int p = 0; p < 4; ++p) {
                    unsigned int t0 = actu32(p0[p], af[2 * p], bfv[2 * p],
                                             af[2 * p + 1], bfv[2 * p + 1]);
                    unsigned int t1 = actu32(p1[p], af[8 + 2 * p], bfv[8 + 2 * p],
                                             af[8 + 2 * p + 1], bfv[8 + 2 * p + 1]);
                    p0[p] = inv ? 0u : t0;
                    p1[p] = inv ? 0u : t1;
                }
            }
            afr[mt][0] = __builtin_bit_cast(bf16x8, r0);
            afr[mt][1] = __builtin_bit_cast(bf16x8, r1);
        }

        __builtin_amdgcn_s_setprio(1);
#pragma unroll
        for (int mt = 0; mt < 2; ++mt) {
#pragma unroll
            for (int nt = 0; nt < 4; ++nt) {
                acc[mt][nt] = __builtin_amdgcn_mfma_f32_16x16x32_bf16(afr[mt][0], B[0][nt], acc[mt][nt], 0, 0, 0);
                acc[mt][nt] = __builtin_amdgcn_mfma_f32_16x16x32_bf16(afr[mt][1], B[1][nt], acc[mt][nt], 0, 0, 0);
            }
        }
        __builtin_amdgcn_s_setprio(0);
    }

    // ---- per-channel stats: C/D layout ch = nt*16 + l15, site = mt*16 + 4*quad + r ----
    float ss[4] = {0.f, 0.f, 0.f, 0.f};
    float sq[4] = {0.f, 0.f, 0.f, 0.f};
#pragma unroll
    for (int mt = 0; mt < 2; ++mt)
#pragma unroll
        for (int nt = 0; nt < 4; ++nt)
#pragma unroll
            for (int r = 0; r < 4; ++r) {
                float v = acc[mt][nt][r];
                ss[nt] += v;
                sq[nt] += v * v;
            }
#pragma unroll
    for (int nt = 0; nt < 4; ++nt) {
        ss[nt] += __shfl_xor(ss[nt], 16);
        ss[nt] += __shfl_xor(ss[nt], 32);
        sq[nt] += __shfl_xor(sq[nt], 16);
        sq[nt] += __shfl_xor(sq[nt], 32);
    }
    if (lane < 16) {
#pragma unroll
        for (int nt = 0; nt < 4; ++nt) {
            atomicAdd(&bs_sum[nt * 16 + l15], ss[nt]);
            atomicAdd(&bs_sq[nt * 16 + l15], sq[nt]);
        }
    }

    // ---- store ----
    if constexpr (OUT_BF16) {
        __shared__ ushort_t tr[4 * 32 * 72];
        ushort_t* w_tr = tr + wv * 32 * 72;
#pragma unroll
        for (int mt = 0; mt < 2; ++mt)
#pragma unroll
            for (int nt = 0; nt < 4; ++nt)
#pragma unroll
                for (int r = 0; r < 4; ++r)
                    w_tr[(mt * 16 + 4 * quad + r) * 72 + nt * 16 + l15] = f2bf(acc[mt][nt][r]);
        // wave-private region: lgkmcnt ordering only, no barrier needed
        int site_s = lane >> 1;
        int half = lane & 1;
        int gs = sbase + site_s;
        if (gs < NSITES) {
#pragma unroll
            for (int c = 0; c < 4; ++c) {
                uint4 d = *(const uint4*)(w_tr + site_s * 72 + half * 32 + c * 8);
                *(uint4*)(out_bf + (size_t)gs * 64 + half * 32 + c * 8) = d;
            }
        }
    } else {
#pragma unroll
        for (int mt = 0; mt < 2; ++mt)
#pragma unroll
            for (int nt = 0; nt < 4; ++nt)
#pragma unroll
                for (int r = 0; r < 4; ++r) {
                    int site = sbase + mt * 16 + 4 * quad + r;
                    if (site < NSITES)
                        out_f[(size_t)site * 64 + nt * 16 + l15] = acc[mt][nt][r];
                }
    }

    __syncthreads();
    if (tid < 64) {
        atomicAdd(&s_sum[tid], bs_sum[tid]);
        atomicAdd(&s_sq[tid], bs_sq[tid]);
    }
}

// ---------------- residual epilogue with fused BN2 finalize ----------------
__global__ void residual_kernel(float* __restrict__ out, const float* __restrict__ feat,
                                const float* __restrict__ sum2, const float* __restrict__ sq2,
                                const float* __restrict__ gamma2, const float* __restrict__ beta2,
                                int total8) {
    __shared__ __align__(16) float sa[64];
    __shared__ __align__(16) float sb[64];
    if (threadIdx.x < 64) {
        int c = threadIdx.x;
        float m = sum2[c] * INV_N;
        float v = sq2[c] * INV_N - m * m;
        float s = gamma2[c] * rsqrtf(v + EPS_BN);
        sa[c] = s;
        sb[c] = beta2[c] - m * s;
    }
    __syncthreads();
    int stride = gridDim.x * blockDim.x;
    for (int i = blockIdx.x * blockDim.x + threadIdx.x; i < total8; i += stride) {
        float4* op = (float4*)(out + (size_t)i * 8);
        const float4* fp = (const float4*)(feat + (size_t)i * 8);
        float4 h0 = op[0];
        float4 h1v = op[1];
        float4 f0 = fp[0];
        float4 f1 = fp[1];
        int c8 = (i & 7) * 8;
        float4 av0 = *(const float4*)&sa[c8];
        float4 av1 = *(const float4*)&sa[c8 + 4];
        float4 bv0 = *(const float4*)&sb[c8];
        float4 bv1 = *(const float4*)&sb[c8 + 4];
        float4 r0, r1;
        r0.x = fmaxf(av0.x * h0.x + bv0.x + f0.x, 0.f);
        r0.y = fmaxf(av0.y * h0.y + bv0.y + f0.y, 0.f);
        r0.z = fmaxf(av0.z * h0.z + bv0.z + f0.z, 0.f);
        r0.w = fmaxf(av0.w * h0.w + bv0.w + f0.w, 0.f);
        r1.x = fmaxf(av1.x * h1v.x + bv1.x + f1.x, 0.f);
        r1.y = fmaxf(av1.y * h1v.y + bv1.y + f1.y, 0.f);
        r1.z = fmaxf(av1.z * h1v.z + bv1.z + f1.z, 0.f);
        r1.w = fmaxf(av1.w * h1v.w + bv1.w + f1.w, 0.f);
        op[0] = r0;
        op[1] = r1;
    }
}

extern "C" void kernel_launch(void* const* d_in, const int* in_sizes, int n_in,
                              void* d_out, int out_size, void* d_ws, size_t ws_size,
                              hipStream_t stream) {
    const float* features = (const float*)d_in[0];
    const int* nbr        = (const int*)d_in[1];
    const float* W1       = (const float*)d_in[2];
    const float* gamma1   = (const float*)d_in[3];
    const float* beta1    = (const float*)d_in[4];
    const float* W2       = (const float*)d_in[5];
    const float* gamma2   = (const float*)d_in[6];
    const float* beta2    = (const float*)d_in[7];

    char* ws = (char*)d_ws;
    const size_t NB = (size_t)NSITES * CCH * sizeof(unsigned short);  // 128,000,000 B

    // fbf in d_out's first half (+zero row); dead once conv2 overwrites d_out with fp32 h2
    ushort_t* fbf = (ushort_t*)d_out;                 // [N+1][64] bf16
    ushort_t* h1  = (ushort_t*)ws;                    // [N][64] bf16
    size_t off = NB + 512;
    ushort_t* W1s = (ushort_t*)(ws + off);            // 147456 B
    ushort_t* W2s = (ushort_t*)(ws + off + 147456);   // 147456 B
    float* stats  = (float*)(ws + off + 294912);      // sum1,sq1,sum2,sq2 (4*64 fp32)

    prep_kernel<<<8192, 256, 0, stream>>>(features, fbf, W1, W2, W1s, W2s, stats,
                                          NSITES * CCH / 16);

    const int nblk = (NSITES + 127) / 128;  // 7813
    conv_kernel<true, false><<<nblk, 256, 0, stream>>>(
        fbf, nbr, W1s, nullptr, nullptr, nullptr, nullptr,
        h1, nullptr, stats + 0, stats + 64);

    conv_kernel<false, true><<<nblk, 256, 0, stream>>>(
        h1, nbr, W2s, stats + 0, stats + 64, gamma1, beta1,
        nullptr, (float*)d_out, stats + 128, stats + 192);

    residual_kernel<<<8192, 256, 0, stream>>>((float*)d_out, features,
                                              stats + 128, stats + 192, gamma2, beta2,
                                              NSITES * CCH / 8);
}

// Round 3
// 974.608 us; speedup vs baseline: 1.4808x; 1.4808x over previous
//
#include <hip/hip_runtime.h>

#define NSITES 1000000
#define CCH 64
#define EPS_BN 1e-5f
#define INV_N (1.0f / 1000000.0f)

typedef __bf16 bf16x8 __attribute__((ext_vector_type(8)));
typedef float f32x4 __attribute__((ext_vector_type(4)));
typedef unsigned short ushort_t;

__device__ __forceinline__ unsigned short f2bf(float x) {
    __bf16 h = (__bf16)x;
    return __builtin_bit_cast(unsigned short, h);
}
__device__ __forceinline__ float bf2f(unsigned short u) {
    return (float)__builtin_bit_cast(__bf16, u);
}

// BN1+ReLU applied to a packed pair of bf16 (identical math to the old act_kernel:
// f32 unpack -> a*x+b -> relu -> bf16 round). Bit-identical to the former h1 pass.
__device__ __forceinline__ unsigned int actu32(unsigned int u, float a0, float b0,
                                               float a1, float b1) {
    float x0 = __builtin_bit_cast(float, u << 16);
    float x1 = __builtin_bit_cast(float, u & 0xffff0000u);
    float y0 = fmaxf(a0 * x0 + b0, 0.f);
    float y1 = fmaxf(a1 * x1 + b1, 0.f);
    return (unsigned int)f2bf(y0) | ((unsigned int)f2bf(y1) << 16);
}

// ---------------- prep: cast fp32->bf16 + W swizzle + stats/zero-row init ----------------
__global__ void prep_kernel(const float* __restrict__ f, ushort_t* __restrict__ o,
                            const float* __restrict__ W1, const float* __restrict__ W2,
                            ushort_t* __restrict__ W1s, ushort_t* __restrict__ W2s,
                            float* __restrict__ stats, int total16) {
    int gtid = blockIdx.x * blockDim.x + threadIdx.x;
    if (gtid < 73728) {
        // swizzle W (fp32 [9][64][64]) into B-fragment order bf16
        // u = (((tap*2+kk)*4 + nt)*64 + lane)*8 + j
        // -> W[tap][k = 32*kk + 8*(lane>>4) + j][n = 16*nt + (lane&15)]
        const float* Wg = W1;
        ushort_t* dst = W1s;
        int u = gtid;
        if (u >= 36864) { Wg = W2; dst = W2s; u -= 36864; }
        int j = u & 7;
        int lane = (u >> 3) & 63;
        int nt = (u >> 9) & 3;
        int kk = (u >> 11) & 1;
        int tap = u >> 12;
        int k = 32 * kk + 8 * (lane >> 4) + j;
        int n = 16 * nt + (lane & 15);
        dst[u] = f2bf(Wg[tap * 4096 + k * 64 + n]);
    } else if (gtid < 73984) {
        stats[gtid - 73728] = 0.f;            // sum1,sq1,sum2,sq2
    } else if (gtid < 74016) {
        ((unsigned int*)(o + (size_t)NSITES * 64))[gtid - 73984] = 0u;  // fbf zero row
    }
    int stride = gridDim.x * blockDim.x;
    for (int i = gtid; i < total16; i += stride) {
        const float4* fp = (const float4*)(f + (size_t)i * 16);
        float4 v0 = fp[0];
        float4 v1 = fp[1];
        float4 v2 = fp[2];
        float4 v3 = fp[3];
        uint4 pa, pb;
        ushort_t* up = (ushort_t*)&pa;
        up[0] = f2bf(v0.x); up[1] = f2bf(v0.y); up[2] = f2bf(v0.z); up[3] = f2bf(v0.w);
        up[4] = f2bf(v1.x); up[5] = f2bf(v1.y); up[6] = f2bf(v1.z); up[7] = f2bf(v1.w);
        ushort_t* uq = (ushort_t*)&pb;
        uq[0] = f2bf(v2.x); uq[1] = f2bf(v2.y); uq[2] = f2bf(v2.z); uq[3] = f2bf(v2.w);
        uq[4] = f2bf(v3.x); uq[5] = f2bf(v3.y); uq[6] = f2bf(v3.z); uq[7] = f2bf(v3.w);
        uint4* op = (uint4*)(o + (size_t)i * 16);
        op[0] = pa;
        op[1] = pb;
    }
}

// ---------------- A-fragment gather: 2 m-tiles x 2 k-frags, direct from global ----------------
__device__ __forceinline__ void gatherA(const ushort_t* __restrict__ fin,
                                        const int (&idxr)[2][9], int t, int quad,
                                        uint4 (&dst)[2][2], int fallback) {
#pragma unroll
    for (int mt = 0; mt < 2; ++mt) {
        int id = idxr[mt][t];
        int r = (id < 0) ? fallback : id;
        const uint4* p = (const uint4*)(fin + ((size_t)r << 6) + (quad << 3));
        dst[mt][0] = p[0];   // k = 0..31 slice
        dst[mt][1] = p[4];   // k = 32..63 slice
    }
}

// ---------------- conv kernel: barrier-free, wave = 32 sites x 64 ch ----------------
// FUSE_ACT: apply BN1+ReLU (from prev-conv stats) to gathered rows; invalid -> 0 via cndmask.
// NOTE: no min-waves arg in launch_bounds — round 2 showed that pinning waves/EU caps
// VGPR at 64 and spills the whole tap loop to scratch (WRITE_SIZE 254MB -> 1.55GB).
template <bool OUT_BF16, bool FUSE_ACT>
__global__ __launch_bounds__(256) void conv_kernel(
    const ushort_t* __restrict__ fin,   // [N(+1)][64] bf16
    const int* __restrict__ nbr,        // [N][9]
    const ushort_t* __restrict__ Wsw,   // swizzled bf16 W fragments
    const float* __restrict__ p_sum, const float* __restrict__ p_sq,
    const float* __restrict__ p_gamma, const float* __restrict__ p_beta,
    ushort_t* __restrict__ out_bf, float* __restrict__ out_f,
    float* __restrict__ s_sum, float* __restrict__ s_sq) {

    __shared__ float bs_sum[64];
    __shared__ float bs_sq[64];
    __shared__ __align__(16) float s_a[64];
    __shared__ __align__(16) float s_b[64];

    const int tid  = threadIdx.x;
    const int wv   = tid >> 6;
    const int lane = tid & 63;
    const int quad = lane >> 4;
    const int l15  = lane & 15;
    const int sbase = blockIdx.x * 128 + wv * 32;

    if (tid < 64) {
        bs_sum[tid] = 0.f;
        bs_sq[tid] = 0.f;
        if constexpr (FUSE_ACT) {
            // per-block BN1 finalize (stats are global sums from conv1)
            float m = p_sum[tid] * INV_N;
            float v = p_sq[tid] * INV_N - m * m;
            float s = p_gamma[tid] * rsqrtf(v + EPS_BN);
            s_a[tid] = s;
            s_b[tid] = p_beta[tid] - m * s;
        }
    }
    __syncthreads();

    float af[16], bfv[16];
    if constexpr (FUSE_ACT) {
#pragma unroll
        for (int j = 0; j < 8; ++j) {
            af[j]      = s_a[quad * 8 + j];
            af[8 + j]  = s_a[32 + quad * 8 + j];
            bfv[j]     = s_b[quad * 8 + j];
            bfv[8 + j] = s_b[32 + quad * 8 + j];
        }
    }

    // preload all 18 neighbor indices (tail sites forced invalid)
    int idxr[2][9];
#pragma unroll
    for (int mt = 0; mt < 2; ++mt) {
        int s = sbase + mt * 16 + l15;
        int sc = (s < NSITES) ? s : 0;
        bool sv = (s < NSITES);
#pragma unroll
        for (int t = 0; t < 9; ++t) {
            int id = nbr[(size_t)sc * 9 + t];
            idxr[mt][t] = sv ? id : -1;
        }
    }

    f32x4 acc[2][4];
#pragma unroll
    for (int mt = 0; mt < 2; ++mt)
#pragma unroll
        for (int nt = 0; nt < 4; ++nt) acc[mt][nt] = (f32x4){0.f, 0.f, 0.f, 0.f};

    constexpr int FB = FUSE_ACT ? 0 : NSITES;  // conv1: zero row; conv2: any row, cndmask'd

    uint4 abuf[2][2][2];  // [phase][mt][kk]
    gatherA(fin, idxr, 0, quad, abuf[0], FB);

#pragma unroll
    for (int t = 0; t < 9; ++t) {
        // B fragments FIRST (so the MFMA waitcnt keeps next-tap gathers in flight)
        bf16x8 B[2][4];
#pragma unroll
        for (int kk = 0; kk < 2; ++kk)
#pragma unroll
            for (int nt = 0; nt < 4; ++nt)
                B[kk][nt] = *(const bf16x8*)(Wsw + (size_t)(((t * 2 + kk) * 4 + nt) * 64 + lane) * 8);

        if (t < 8) gatherA(fin, idxr, t + 1, quad, abuf[(t + 1) & 1], FB);

        // prepare A fragments (act + invalid->0 for conv2)
        bf16x8 afr[2][2];
#pragma unroll
        for (int mt = 0; mt < 2; ++mt) {
            uint4 r0 = abuf[t & 1][mt][0];
            uint4 r1 = abuf[t & 1][mt][1];
            if constexpr (FUSE_ACT) {
                bool inv = idxr[mt][t] < 0;
                unsigned int* p0 = (unsigned int*)&r0;
                unsigned int* p1 = (unsigned int*)&r1;
#pragma unroll
                for (int p = 0; p < 4; ++p) {
                    unsigned int t0 = actu32(p0[p], af[2 * p], bfv[2 * p],
                                             af[2 * p + 1], bfv[2 * p + 1]);
                    unsigned int t1 = actu32(p1[p], af[8 + 2 * p], bfv[8 + 2 * p],
                                             af[8 + 2 * p + 1], bfv[8 + 2 * p + 1]);
                    p0[p] = inv ? 0u : t0;
                    p1[p] = inv ? 0u : t1;
                }
            }
            afr[mt][0] = __builtin_bit_cast(bf16x8, r0);
            afr[mt][1] = __builtin_bit_cast(bf16x8, r1);
        }

        __builtin_amdgcn_s_setprio(1);
#pragma unroll
        for (int mt = 0; mt < 2; ++mt) {
#pragma unroll
            for (int nt = 0; nt < 4; ++nt) {
                acc[mt][nt] = __builtin_amdgcn_mfma_f32_16x16x32_bf16(afr[mt][0], B[0][nt], acc[mt][nt], 0, 0, 0);
                acc[mt][nt] = __builtin_amdgcn_mfma_f32_16x16x32_bf16(afr[mt][1], B[1][nt], acc[mt][nt], 0, 0, 0);
            }
        }
        __builtin_amdgcn_s_setprio(0);
    }

    // ---- per-channel stats: C/D layout ch = nt*16 + l15, site = mt*16 + 4*quad + r ----
    float ss[4] = {0.f, 0.f, 0.f, 0.f};
    float sq[4] = {0.f, 0.f, 0.f, 0.f};
#pragma unroll
    for (int mt = 0; mt < 2; ++mt)
#pragma unroll
        for (int nt = 0; nt < 4; ++nt)
#pragma unroll
            for (int r = 0; r < 4; ++r) {
                float v = acc[mt][nt][r];
                ss[nt] += v;
                sq[nt] += v * v;
            }
#pragma unroll
    for (int nt = 0; nt < 4; ++nt) {
        ss[nt] += __shfl_xor(ss[nt], 16);
        ss[nt] += __shfl_xor(ss[nt], 32);
        sq[nt] += __shfl_xor(sq[nt], 16);
        sq[nt] += __shfl_xor(sq[nt], 32);
    }
    if (lane < 16) {
#pragma unroll
        for (int nt = 0; nt < 4; ++nt) {
            atomicAdd(&bs_sum[nt * 16 + l15], ss[nt]);
            atomicAdd(&bs_sq[nt * 16 + l15], sq[nt]);
        }
    }

    // ---- store ----
    if constexpr (OUT_BF16) {
        __shared__ ushort_t tr[4 * 32 * 72];
        ushort_t* w_tr = tr + wv * 32 * 72;
#pragma unroll
        for (int mt = 0; mt < 2; ++mt)
#pragma unroll
            for (int nt = 0; nt < 4; ++nt)
#pragma unroll
                for (int r = 0; r < 4; ++r)
                    w_tr[(mt * 16 + 4 * quad + r) * 72 + nt * 16 + l15] = f2bf(acc[mt][nt][r]);
        // wave-private region: lgkmcnt ordering only, no barrier needed
        int site_s = lane >> 1;
        int half = lane & 1;
        int gs = sbase + site_s;
        if (gs < NSITES) {
#pragma unroll
            for (int c = 0; c < 4; ++c) {
                uint4 d = *(const uint4*)(w_tr + site_s * 72 + half * 32 + c * 8);
                *(uint4*)(out_bf + (size_t)gs * 64 + half * 32 + c * 8) = d;
            }
        }
    } else {
#pragma unroll
        for (int mt = 0; mt < 2; ++mt)
#pragma unroll
            for (int nt = 0; nt < 4; ++nt)
#pragma unroll
                for (int r = 0; r < 4; ++r) {
                    int site = sbase + mt * 16 + 4 * quad + r;
                    if (site < NSITES)
                        out_f[(size_t)site * 64 + nt * 16 + l15] = acc[mt][nt][r];
                }
    }

    __syncthreads();
    if (tid < 64) {
        atomicAdd(&s_sum[tid], bs_sum[tid]);
        atomicAdd(&s_sq[tid], bs_sq[tid]);
    }
}

// ---------------- residual epilogue with fused BN2 finalize ----------------
__global__ void residual_kernel(float* __restrict__ out, const float* __restrict__ feat,
                                const float* __restrict__ sum2, const float* __restrict__ sq2,
                                const float* __restrict__ gamma2, const float* __restrict__ beta2,
                                int total8) {
    __shared__ __align__(16) float sa[64];
    __shared__ __align__(16) float sb[64];
    if (threadIdx.x < 64) {
        int c = threadIdx.x;
        float m = sum2[c] * INV_N;
        float v = sq2[c] * INV_N - m * m;
        float s = gamma2[c] * rsqrtf(v + EPS_BN);
        sa[c] = s;
        sb[c] = beta2[c] - m * s;
    }
    __syncthreads();
    int stride = gridDim.x * blockDim.x;
    for (int i = blockIdx.x * blockDim.x + threadIdx.x; i < total8; i += stride) {
        float4* op = (float4*)(out + (size_t)i * 8);
        const float4* fp = (const float4*)(feat + (size_t)i * 8);
        float4 h0 = op[0];
        float4 h1v = op[1];
        float4 f0 = fp[0];
        float4 f1 = fp[1];
        int c8 = (i & 7) * 8;
        float4 av0 = *(const float4*)&sa[c8];
        float4 av1 = *(const float4*)&sa[c8 + 4];
        float4 bv0 = *(const float4*)&sb[c8];
        float4 bv1 = *(const float4*)&sb[c8 + 4];
        float4 r0, r1;
        r0.x = fmaxf(av0.x * h0.x + bv0.x + f0.x, 0.f);
        r0.y = fmaxf(av0.y * h0.y + bv0.y + f0.y, 0.f);
        r0.z = fmaxf(av0.z * h0.z + bv0.z + f0.z, 0.f);
        r0.w = fmaxf(av0.w * h0.w + bv0.w + f0.w, 0.f);
        r1.x = fmaxf(av1.x * h1v.x + bv1.x + f1.x, 0.f);
        r1.y = fmaxf(av1.y * h1v.y + bv1.y + f1.y, 0.f);
        r1.z = fmaxf(av1.z * h1v.z + bv1.z + f1.z, 0.f);
        r1.w = fmaxf(av1.w * h1v.w + bv1.w + f1.w, 0.f);
        op[0] = r0;
        op[1] = r1;
    }
}

extern "C" void kernel_launch(void* const* d_in, const int* in_sizes, int n_in,
                              void* d_out, int out_size, void* d_ws, size_t ws_size,
                              hipStream_t stream) {
    const float* features = (const float*)d_in[0];
    const int* nbr        = (const int*)d_in[1];
    const float* W1       = (const float*)d_in[2];
    const float* gamma1   = (const float*)d_in[3];
    const float* beta1    = (const float*)d_in[4];
    const float* W2       = (const float*)d_in[5];
    const float* gamma2   = (const float*)d_in[6];
    const float* beta2    = (const float*)d_in[7];

    char* ws = (char*)d_ws;
    const size_t NB = (size_t)NSITES * CCH * sizeof(unsigned short);  // 128,000,000 B

    // fbf in d_out's first half (+zero row); dead once conv2 overwrites d_out with fp32 h2
    ushort_t* fbf = (ushort_t*)d_out;                 // [N+1][64] bf16
    ushort_t* h1  = (ushort_t*)ws;                    // [N][64] bf16
    size_t off = NB + 512;
    ushort_t* W1s = (ushort_t*)(ws + off);            // 147456 B
    ushort_t* W2s = (ushort_t*)(ws + off + 147456);   // 147456 B
    float* stats  = (float*)(ws + off + 294912);      // sum1,sq1,sum2,sq2 (4*64 fp32)

    prep_kernel<<<8192, 256, 0, stream>>>(features, fbf, W1, W2, W1s, W2s, stats,
                                          NSITES * CCH / 16);

    const int nblk = (NSITES + 127) / 128;  // 7813
    conv_kernel<true, false><<<nblk, 256, 0, stream>>>(
        fbf, nbr, W1s, nullptr, nullptr, nullptr, nullptr,
        h1, nullptr, stats + 0, stats + 64);

    conv_kernel<false, true><<<nblk, 256, 0, stream>>>(
        h1, nbr, W2s, stats + 0, stats + 64, gamma1, beta1,
        nullptr, (float*)d_out, stats + 128, stats + 192);

    residual_kernel<<<8192, 256, 0, stream>>>((float*)d_out, features,
                                              stats + 128, stats + 192, gamma2, beta2,
                                              NSITES * CCH / 8);
}